// Round 16
// baseline (281.045 us; speedup 1.0000x reference)
//
#include <hip/hip_runtime.h>
#include <hip/hip_bf16.h>
#include <math.h>

#define SEQ_LEN 128
#define BATCH   32
#define T       32
#define TT      (T*T)     // 1024
#define TTT     (T*T*T)   // 32768
#define START   30
#define END     31

#define LOG2E   1.44269504088896f
#define OFF4    5.77078016355587f   // 4 * log2(e)

typedef unsigned long long u64;

__device__ __forceinline__ u64 pt_pack(int tag, float v) {
    union { float f; unsigned int u; } c; c.f = v;
    return ((u64)(unsigned int)tag << 32) | (u64)c.u;
}
__device__ __forceinline__ float pt_val(u64 w) {
    union { unsigned int u; float f; } c; c.u = (unsigned int)w; return c.f;
}
__device__ __forceinline__ int pt_tag(u64 w) { return (int)(w >> 32); }

__device__ __forceinline__ u64 ald64(const u64* p) {
    return __hip_atomic_load(p, __ATOMIC_RELAXED, __HIP_MEMORY_SCOPE_AGENT);
}
__device__ __forceinline__ void ast64(u64* p, u64 v) {
    __hip_atomic_store(p, v, __ATOMIC_RELAXED, __HIP_MEMORY_SCOPE_AGENT);
}

// raw barrier: drain LDS ops only; global prefetch/publish stay in flight
#define BLOCK_SYNC() do {                                   \
    asm volatile("s_waitcnt lgkmcnt(0)" ::: "memory");      \
    __builtin_amdgcn_sched_barrier(0);                      \
    __builtin_amdgcn_s_barrier();                           \
    __builtin_amdgcn_sched_barrier(0);                      \
} while (0)

// ---------------------------------------------------------------------------
// Kernel: distributed fwd/bwd scan, wave0 = PURE POLLER (no tile loads ever,
// so its vmcnt queue holds only poll loads -> detect ~= MALL RT, not HBM
// streaming latency). 512 blocks x 320 threads (5 waves), 2 blocks/CU
// co-resident (LDS 68.6KB x2 < 160KB). g=bid&7, chain=bid>>3, b=chain&31,
// dirB=chain>=32. Protocol identical to r11 (proven absmax 0): per-word
// tagged u64, 2 parity buffers, wave0 polls its contiguous 128-word range
// every step, one barrier per step, publishes after the barrier (the r8
// certification induction).
//  Roles: wave0: tg-gather prologue + first-hop local state + poll->pld.
//         waves1-4 (256 thr): fwd tile staging (4 f4/thread) + compute
//         (2 thr/output, 16 MAC + shfl_xor(1)) + publish (h==0 lanes).
//  First hops are LOCAL (fwd: Q_1 = exp(p1+s1) computed in-block; bwd:
//  R_127 = indicator) -> no init kernel; tag-clear via hipMemsetAsync(0)
//  (consumed tags are >= 2, 0 never matches; replay-safe: memset is in
//  the captured graph).
// ---------------------------------------------------------------------------
__global__ __launch_bounds__(320, 3) void scan_pi(const float* __restrict__ scores,
                                                  const int*   __restrict__ target,
                                                  const int*   __restrict__ maskI,
                                                  u64*         __restrict__ ptF,
                                                  u64*         __restrict__ ptB,
                                                  float*       __restrict__ wsg) {
    const int bid   = blockIdx.x;
    const int g     = bid & 7;
    const int chain = bid >> 3;
    const int b     = chain & 31;
    const bool dirB = (chain >> 5) != 0;
    const int tid   = threadIdx.x;
    const int lane  = tid & 63;

    __shared__ __align__(16) float sm[4][128 * 33];   // fwd tile ring
    __shared__ float pld[2][128];                     // polled state chunks

    // mask as wave-uniform bitfields
    const u64 mlo = __ballot(maskI[lane * BATCH + b] != 0);
    const u64 mhi = __ballot(maskI[(64 + lane) * BATCH + b] != 0);
    auto act_of = [&](int t) {
        return (((t < 64) ? (mlo >> t) : (mhi >> (t - 64))) & 1ULL) != 0ULL;
    };

    u64* const pt = (dirB ? ptB : ptF) + (size_t)b * 2048;
    auto sb = [&](int t) { return scores + ((size_t)t * BATCH + b) * TTT; };

    // ---- wave0 prologue: tg gather (8 pairs per block) ----
    if (tid < 64) {
        const int idx = bid * 8 + lane;
        float tv = 0.f;
        if (lane < 8 && maskI[idx] != 0)
            tv = scores[(size_t)idx * TTT + target[idx]];
        #pragma unroll
        for (int off = 32; off > 0; off >>= 1) tv += __shfl_xor(tv, off, 64);
        if (lane == 0) wsg[bid] = tv;
    }

    const int ct  = tid - 64;              // compute-thread index (tid>=64)
    const int out = ct >> 1;               // 0..127
    const int h   = ct & 1;

    if (!dirB) {
        // ------------------------------ FORWARD ------------------------------
        // steps t=2..64: Q_t[j,k] = sum_i E_t[i,j,k] Q_{t-1}[i,j], j in Jc.
        const int jj   = out >> 5, k = out & 31;
        const int jcol = 4 * g + jj;
        const int ownW = k * 32 + jcol;

        float lastval = 0.f;
        float4 fv[4];

        auto issueT = [&](int t) {
            const float* base = sb(t) + g * 128;
            #pragma unroll
            for (int n = 0; n < 4; ++n) {
                const int p = ct + 256 * n;
                fv[n] = *(const float4*)(base + (size_t)(p >> 5) * TT + (p & 31) * 4);
            }
        };
        auto scatT = [&](int buf) {
            #pragma unroll
            for (int n = 0; n < 4; ++n) {
                const int p = ct + 256 * n;
                const int i = p >> 5, r0 = (p & 31) * 4;
                sm[buf][(r0 + 0) * 33 + i] = fv[n].x;
                sm[buf][(r0 + 1) * 33 + i] = fv[n].y;
                sm[buf][(r0 + 2) * 33 + i] = fv[n].z;
                sm[buf][(r0 + 3) * 33 + i] = fv[n].w;
            }
        };

        if (tid >= 64) {
            if (h == 0) {   // local init of own word of Q_1 (masked-path cache)
                float p1v = scores[(size_t)(0*BATCH + b)*TTT + START*TT + START*T + jcol];
                float s1v = scores[(size_t)(1*BATCH + b)*TTT + START*TT + jcol*T + k];
                lastval = __expf(p1v + s1v);
            }
            issueT(2); scatT(2);
            issueT(3); scatT(3);
            issueT(4);
        } else {
            // local init of pld for t=2 (no poll needed at first hop)
            const float* s0b = scores + (size_t)(0*BATCH + b)*TTT + START*TT + START*T;
            const float* s1b = scores + (size_t)(1*BATCH + b)*TTT + START*TT;
            const int x0 = lane, x1 = lane + 64;
            pld[0][x0] = __expf(s0b[x0 & 31] + s1b[(x0 & 31)*T + 4*g + (x0 >> 5)]);
            pld[0][x1] = __expf(s0b[x1 & 31] + s1b[(x1 & 31)*T + 4*g + (x1 >> 5)]);
        }
        __syncthreads();

        for (int t = 2; t <= 64; ++t) {
            const bool act  = act_of(t);
            const int  pbuf = t & 1;
            if (tid >= 64) {
                if (t + 2 <= 64) scatT((t + 2) & 3);
                if (t + 3 <= 64) issueT(t + 3);
            } else if (t > 2) {
                // poll own 128-word range, tag t-1 (vmem queue: poll only)
                const int tagw = t - 1;
                const u64* src = pt + (size_t)((t - 1) & 1) * 1024 + 128 * g;
                u64 a0, a1; bool d0 = false, d1 = false;
                for (;;) {
                    if (!d0) { a0 = ald64(src + lane);      d0 = pt_tag(a0) == tagw; }
                    if (!d1) { a1 = ald64(src + 64 + lane); d1 = pt_tag(a1) == tagw; }
                    if (__all(d0 && d1)) break;
                }
                pld[pbuf][lane]      = pt_val(a0);
                pld[pbuf][lane + 64] = pt_val(a1);
            }
            BLOCK_SYNC();   // pld + tile buf(t&3) ready; certifies prior reads
            if (tid >= 64) {
                u64* dst = pt + (size_t)(t & 1) * 1024;
                if (act) {
                    const float* row = &sm[t & 3][out * 33 + 16 * h];
                    const float* pp  = &pld[pbuf][jj * 32 + 16 * h];
                    float acc = 0.f;
                    #pragma unroll
                    for (int m = 0; m < 16; ++m)
                        acc = fmaf(exp2f(fmaf(row[m], LOG2E, -OFF4)), pp[m], acc);
                    acc += __shfl_xor(acc, 1, 64);
                    if (h == 0) { lastval = acc; ast64(dst + ownW, pt_pack(t, acc)); }
                } else {
                    if (h == 0) ast64(dst + ownW, pt_pack(t, lastval));
                }
            }
        }
    } else {
        // ------------------------------ BACKWARD ------------------------------
        // steps t=127..65: R_{t-1}[i,j] = sum_k E_t[i,j,k] R_t[j,k], j in Jc.
        const int i   = out >> 2, jjB = out & 3;
        const int jb  = 4 * g + jjB;
        const int ownW = i * 32 + jb;
        float lastval = (i == END && jb == END) ? 1.0f : 0.0f;

        float4 EA[4], EB[4];
        auto issueE = [&](float4* E, int t) {
            const float* p = sb(t) + (size_t)i * TT + jb * 32 + 16 * h;
            E[0] = *(const float4*)(p + 0);
            E[1] = *(const float4*)(p + 4);
            E[2] = *(const float4*)(p + 8);
            E[3] = *(const float4*)(p + 12);
        };
        auto pollB = [&](int t) {   // consumes tag t+1 -> pld[t&1]
            const int tagw = t + 1;
            const u64* src = pt + (size_t)((t + 1) & 1) * 1024 + 128 * g;
            u64 a0, a1; bool d0 = false, d1 = false;
            for (;;) {
                if (!d0) { a0 = ald64(src + lane);      d0 = pt_tag(a0) == tagw; }
                if (!d1) { a1 = ald64(src + 64 + lane); d1 = pt_tag(a1) == tagw; }
                if (__all(d0 && d1)) break;
            }
            pld[t & 1][lane]      = pt_val(a0);
            pld[t & 1][lane + 64] = pt_val(a1);
        };
        auto computeB = [&](int t, const float4* E) {
            const bool act  = act_of(t);
            const int  pbuf = t & 1;
            u64* dst = pt + (size_t)(t & 1) * 1024;
            if (act) {
                const float* pp = &pld[pbuf][jjB * 32 + 16 * h];
                float acc = 0.f;
                #pragma unroll
                for (int n = 0; n < 4; ++n) {
                    acc = fmaf(exp2f(fmaf(E[n].x, LOG2E, -OFF4)), pp[n*4 + 0], acc);
                    acc = fmaf(exp2f(fmaf(E[n].y, LOG2E, -OFF4)), pp[n*4 + 1], acc);
                    acc = fmaf(exp2f(fmaf(E[n].z, LOG2E, -OFF4)), pp[n*4 + 2], acc);
                    acc = fmaf(exp2f(fmaf(E[n].w, LOG2E, -OFF4)), pp[n*4 + 3], acc);
                }
                acc += __shfl_xor(acc, 1, 64);
                if (h == 0) { lastval = acc; ast64(dst + ownW, pt_pack(t, acc)); }
            } else {
                if (h == 0) ast64(dst + ownW, pt_pack(t, lastval));
            }
        };

        if (tid >= 64) issueE(EA, 127);
        else {
            // local init of pld for t=127: R_127 indicator
            const int x0 = lane, x1 = lane + 64;
            pld[1][x0] = (4*g + (x0 >> 5) == END && (x0 & 31) == END) ? 1.f : 0.f;
            pld[1][x1] = (4*g + (x1 >> 5) == END && (x1 & 31) == END) ? 1.f : 0.f;
        }
        __syncthreads();

        for (int t = 127; t >= 65; t -= 2) {
            if (tid >= 64 && t - 1 >= 65) issueE(EB, t - 1);
            if (tid < 64 && t < 127) pollB(t);
            BLOCK_SYNC();
            if (tid >= 64) computeB(t, EA);
            if (t - 1 < 65) break;
            if (tid >= 64 && t - 2 >= 65) issueE(EA, t - 2);
            if (tid < 64) pollB(t - 1);
            BLOCK_SYNC();
            if (tid >= 64) computeB(t - 1, EB);
        }
    }
}

// ---------------------------------------------------------------------------
// Finalize. Q_64 = ptF parity0 (tag 64); R_64 = ptB parity1 (tag 65).
// z_b = 4*cnt_b + log( sum Q_64 o R_64 ); tg = sum of 512 block partials.
// ---------------------------------------------------------------------------
__global__ __launch_bounds__(1024) void finalize_pi(const float* __restrict__ wsg,
                                                    const u64*  __restrict__ ptF,
                                                    const u64*  __restrict__ ptB,
                                                    const int*  __restrict__ mask,
                                                    float*      __restrict__ out) {
    __shared__ float zs[32];
    __shared__ float tgp[8];
    const int w = threadIdx.x >> 6, lane = threadIdx.x & 63;

    // tg partial sum (512 block partials)
    {
        float tv = (threadIdx.x < 512) ? wsg[threadIdx.x] : 0.f;
        #pragma unroll
        for (int off = 32; off > 0; off >>= 1) tv += __shfl_xor(tv, off, 64);
        if (lane == 0 && w < 8) tgp[w] = tv;
    }

    for (int rep = 0; rep < 2; ++rep) {
        const int b = w + rep * 16;
        const u64* qf = ptF + (size_t)b * 2048;          // parity0, [k*32+j]
        const u64* rb = ptB + (size_t)b * 2048 + 1024;   // parity1, [i*32+j]
        float dot = 0.f;
        #pragma unroll
        for (int e = 0; e < 16; ++e) {
            const int x = lane + 64 * e;                 // x = k*32 + j
            dot += pt_val(qf[x]) * pt_val(rb[(x & 31) * 32 + (x >> 5)]);
        }
        float cnt = 0.f;
        {
            int t = 2 + lane;
            if (t < SEQ_LEN) cnt += (mask[t*BATCH + b] != 0) ? 1.f : 0.f;
            t += 64;
            if (t < SEQ_LEN) cnt += (mask[t*BATCH + b] != 0) ? 1.f : 0.f;
        }
        #pragma unroll
        for (int off = 32; off > 0; off >>= 1) {
            dot += __shfl_xor(dot, off, 64);
            cnt += __shfl_xor(cnt, off, 64);
        }
        if (lane == 0) zs[b] = 4.0f * cnt + logf(dot);
    }
    __syncthreads();
    if (threadIdx.x == 0) {
        float tg = 0.f, z = 0.f;
        #pragma unroll
        for (int i = 0; i < 8; ++i) tg += tgp[i];
        #pragma unroll
        for (int i = 0; i < 32; ++i) z += zs[i];
        out[0] = (z - tg) / (float)BATCH;
    }
}

// ---------------------------------------------------------------------------
// Fallback (small ws): tg gather + round-5 single-block-per-batch scan.
// ---------------------------------------------------------------------------
__global__ __launch_bounds__(256) void tg_kernel(const float* __restrict__ scores,
                                                 const int*   __restrict__ target,
                                                 const int*   __restrict__ mask,
                                                 float*       __restrict__ ws) {
    int idx = blockIdx.x * 256 + threadIdx.x;
    float v = 0.0f;
    if (mask[idx] != 0) v = scores[(size_t)idx * TTT + target[idx]];
    #pragma unroll
    for (int off = 32; off > 0; off >>= 1) v += __shfl_down(v, off, 64);
    __shared__ float partial[4];
    int wave = threadIdx.x >> 6, lane = threadIdx.x & 63;
    if (lane == 0) partial[wave] = v;
    __syncthreads();
    if (threadIdx.x == 0)
        ws[blockIdx.x] = partial[0] + partial[1] + partial[2] + partial[3];
}

__global__ __launch_bounds__(1024) void scan_fast(const float* __restrict__ scores,
                                                  const int*   __restrict__ maskI,
                                                  float*       __restrict__ ws) {
    const int b    = blockIdx.x;
    const int tid  = threadIdx.x;
    const int w    = tid >> 6;
    const int lane = tid & 63;
    const int h    = lane >> 4;
    const int jp   = (lane >> 3) & 1;
    const int k4   = lane & 7;
    const int j    = w * 2 + jp;

    __shared__ float Q[2][TT];
    __shared__ int   lmask[SEQ_LEN];
    if (tid < SEQ_LEN) lmask[tid] = maskI[tid * BATCH + b];
    {
        int x = tid >> 5, y = tid & 31;
        float p1 = scores[(size_t)(0*BATCH + b)*TTT + START*TT + START*T + x];
        float s1 = scores[(size_t)(1*BATCH + b)*TTT + START*TT + x*T + y];
        Q[1][x*T + y] = __expf(p1 + s1);
    }
    __syncthreads();
    const int loff = h*8*TT + j*T + k4*4;
    float4 SA[8], SB[8];
    auto issue = [&](float4 (&S)[8], int t) {
        const float* p = scores + ((size_t)t*BATCH + b)*TTT + loff;
        #pragma unroll
        for (int m = 0; m < 8; ++m) S[m] = *(const float4*)(p + m*TT);
    };
    auto process = [&](float4 (&S)[8], int t) {
        const float* qc = Q[(t-1) & 1];
        float*       qn = Q[t & 1];
        #pragma unroll
        for (int m = 0; m < 8; ++m) {
            S[m].x = exp2f(fmaf(S[m].x, LOG2E, -OFF4));
            S[m].y = exp2f(fmaf(S[m].y, LOG2E, -OFF4));
            S[m].z = exp2f(fmaf(S[m].z, LOG2E, -OFF4));
            S[m].w = exp2f(fmaf(S[m].w, LOG2E, -OFF4));
        }
        float4 acc = make_float4(0.f, 0.f, 0.f, 0.f);
        #pragma unroll
        for (int m = 0; m < 8; ++m) {
            float q = qc[(h*8 + m)*T + j];
            acc.x = fmaf(S[m].x, q, acc.x);
            acc.y = fmaf(S[m].y, q, acc.y);
            acc.z = fmaf(S[m].z, q, acc.z);
            acc.w = fmaf(S[m].w, q, acc.w);
        }
        acc.x += __shfl_xor(acc.x, 16, 64); acc.y += __shfl_xor(acc.y, 16, 64);
        acc.z += __shfl_xor(acc.z, 16, 64); acc.w += __shfl_xor(acc.w, 16, 64);
        acc.x += __shfl_xor(acc.x, 32, 64); acc.y += __shfl_xor(acc.y, 32, 64);
        acc.z += __shfl_xor(acc.z, 32, 64); acc.w += __shfl_xor(acc.w, 32, 64);
        if (lane < 16) {
            if (lmask[t] != 0) *(float4*)&qn[j*T + k4*4] = acc;
            else               *(float4*)&qn[j*T + k4*4] = *(const float4*)&qc[j*T + k4*4];
        }
        asm volatile("s_waitcnt lgkmcnt(0)" ::: "memory");
        __builtin_amdgcn_s_barrier();
    };
    issue(SA, 2);
    for (int t = 2; t < SEQ_LEN; t += 2) {
        issue(SB, t + 1);
        process(SA, t);
        if (t + 2 < SEQ_LEN) issue(SA, t + 2);
        process(SB, t + 1);
    }
    if (tid == 0) {
        int cnt = 0;
        for (int t = 2; t < SEQ_LEN; ++t) cnt += (lmask[t] != 0);
        ws[16 + b] = 4.0f * (float)cnt + logf(Q[1][END*T + END]);
    }
}

__global__ void finalize_simple(const float* __restrict__ ws, float* __restrict__ out) {
    if (threadIdx.x == 0) {
        float tg = 0.f, z = 0.f;
        #pragma unroll
        for (int i = 0; i < 16; ++i) tg += ws[i];
        #pragma unroll
        for (int i = 0; i < 32; ++i) z += ws[16 + i];
        out[0] = (z - tg) / (float)BATCH;
    }
}

extern "C" void kernel_launch(void* const* d_in, const int* in_sizes, int n_in,
                              void* d_out, int out_size, void* d_ws, size_t ws_size,
                              hipStream_t stream) {
    const float* scores = (const float*)d_in[0];
    const int*   target = (const int*)d_in[1];
    const int*   mask   = (const int*)d_in[2];
    float* out = (float*)d_out;
    float* ws  = (float*)d_ws;
    float* wsg = ws + 32;                                // 512 tg partials
    u64*   ptF = (u64*)((char*)d_ws + 4096);
    u64*   ptB = ptF + (size_t)BATCH * 2048;
    const size_t ptBytes = (size_t)2 * BATCH * 2048 * sizeof(u64);   // 1 MB
    const size_t need = 4096 + ptBytes;

    if (ws_size >= need) {
        hipMemsetAsync((void*)ptF, 0, ptBytes, stream);   // tag-clear (tags>=2 consumed)
        scan_pi<<<512, 320, 0, stream>>>(scores, target, mask, ptF, ptB, wsg);
        finalize_pi<<<1, 1024, 0, stream>>>(wsg, ptF, ptB, mask, out);
    } else {
        tg_kernel<<<16, 256, 0, stream>>>(scores, target, mask, ws);
        scan_fast<<<BATCH, 1024, 0, stream>>>(scores, mask, ws);
        finalize_simple<<<1, 64, 0, stream>>>(ws, out);
    }
}